// Round 10
// baseline (766.947 us; speedup 1.0000x reference)
//
#include <hip/hip_runtime.h>

#define M_BATCH 65536
#define K_IN    1024
#define N_OUT   256

#define BM 128
#define BN 128
#define BK 64
#define LDK 72          // BK + 8 shorts: keeps 16B align, 2-way conflicts max
#define TAU 0.0625f

typedef __attribute__((ext_vector_type(8))) short short8;   // 8 bf16 = 4 VGPR
typedef __attribute__((ext_vector_type(4))) short short4v;
typedef __attribute__((ext_vector_type(4))) float f32x4;

__device__ inline short f2bf(float f) {          // RNE f32 -> bf16 bits
    unsigned u = __builtin_bit_cast(unsigned, f);
    u += 0x7fff + ((u >> 16) & 1);
    return (short)(u >> 16);
}
__device__ inline float bf2f(short s) {
    unsigned u = ((unsigned)(unsigned short)s) << 16;
    return __builtin_bit_cast(float, u);
}

// Bulk: split-bf16 MFMA GEMM (x = hi+lo bf16, w ternary = exact bf16).
// Fast score error vs C3 (r8-verified ref ordering: kc=512 single-chain
// panels) is ~1e-4 RMS, <4e-3 bound; cells with |t+0.5| < TAU get the
// C3-exact inline recompute (r9-proven, absmax 0.0 at same TAU).
__global__ void binlin_mfma(const float* __restrict__ x,
                            const float* __restrict__ w,
                            const float* __restrict__ bias,
                            const float* __restrict__ sign,
                            float* __restrict__ out) {
    __shared__ short Ah[BM][LDK];
    __shared__ short Al[BM][LDK];
    __shared__ short Bh[BN][LDK];

    const int tid  = threadIdx.x;    // 0..255
    const int lane = tid & 63;
    const int wid  = tid >> 6;       // 4 waves, 2x2
    const int wm   = wid >> 1;
    const int wn   = wid & 1;
    const int l15  = lane & 15;
    const int l4   = lane >> 4;

    const int m0 = blockIdx.y * BM;
    const int n0 = blockIdx.x * BN;

    const int srow = tid >> 4;        // 0..15
    const int sk   = (tid & 15) * 4;  // 0..60

    f32x4 acc[4][4];
#pragma unroll
    for (int i = 0; i < 4; ++i)
#pragma unroll
        for (int j = 0; j < 4; ++j) acc[i][j] = (f32x4){0.f, 0.f, 0.f, 0.f};

    for (int kt = 0; kt < K_IN; kt += BK) {
        __syncthreads();
        // stage x tile -> hi/lo bf16 (rows srow+q*16, 4 k-vals each)
#pragma unroll
        for (int q = 0; q < 8; ++q) {
            const int row = srow + q * 16;
            const float4 v = *(const float4*)(x + (size_t)(m0 + row) * K_IN + kt + sk);
            short4v h, l;
            h.x = f2bf(v.x); l.x = f2bf(v.x - bf2f(h.x));
            h.y = f2bf(v.y); l.y = f2bf(v.y - bf2f(h.y));
            h.z = f2bf(v.z); l.z = f2bf(v.z - bf2f(h.z));
            h.w = f2bf(v.w); l.w = f2bf(v.w - bf2f(h.w));
            *(short4v*)&Ah[row][sk] = h;
            *(short4v*)&Al[row][sk] = l;
        }
        // stage w tile -> bf16 (exact: ternary)
#pragma unroll
        for (int q = 0; q < 8; ++q) {
            const int row = srow + q * 16;
            const float4 v = *(const float4*)(w + (size_t)(n0 + row) * K_IN + kt + sk);
            short4v h;
            h.x = f2bf(v.x); h.y = f2bf(v.y); h.z = f2bf(v.z); h.w = f2bf(v.w);
            *(short4v*)&Bh[row][sk] = h;
        }
        __syncthreads();

#pragma unroll
        for (int ks = 0; ks < 2; ++ks) {
            const int ko = ks * 32 + l4 * 8;   // lane's K slice (k = 8*(l>>4)+j)
            short8 bfr[4], ahi[4], alo[4];
#pragma unroll
            for (int ni = 0; ni < 4; ++ni)
                bfr[ni] = *(const short8*)&Bh[wn * 64 + ni * 16 + l15][ko];
#pragma unroll
            for (int mi = 0; mi < 4; ++mi) {
                ahi[mi] = *(const short8*)&Ah[wm * 64 + mi * 16 + l15][ko];
                alo[mi] = *(const short8*)&Al[wm * 64 + mi * 16 + l15][ko];
            }
#pragma unroll
            for (int mi = 0; mi < 4; ++mi)
#pragma unroll
                for (int ni = 0; ni < 4; ++ni) {
                    acc[mi][ni] = __builtin_amdgcn_mfma_f32_16x16x32_bf16(
                        ahi[mi], bfr[ni], acc[mi][ni], 0, 0, 0);
                    acc[mi][ni] = __builtin_amdgcn_mfma_f32_16x16x32_bf16(
                        alo[mi], bfr[ni], acc[mi][ni], 0, 0, 0);
                }
        }
    }

    // epilogue: decision + C3-exact band fixup.
    // D layout (m89-verified): n = lane&15, m = 4*(lane>>4) + reg.
#pragma unroll
    for (int ni = 0; ni < 4; ++ni) {
        const int n = n0 + wn * 64 + ni * 16 + l15;
        const float b = bias[n];
        const float s = sign[n];
#pragma unroll
        for (int mi = 0; mi < 4; ++mi) {
            const int mb = m0 + wm * 64 + mi * 16 + l4 * 4;
#pragma unroll
            for (int j = 0; j < 4; ++j) {
                const int m = mb + j;
                const float t = (acc[mi][ni][j] + b) * s;
                float dec;
                if (fabsf(t + 0.5f) < TAU) {
                    // C3-exact: kc=512 panels, sequential chain each,
                    // cs = panel0 + panel1 (two independent chains -> ILP 2)
                    const float* xr = x + (size_t)m * K_IN;
                    const float* wr = w + (size_t)n * K_IN;
                    float a0 = 0.f, a1 = 0.f;
                    for (int k4 = 0; k4 < 128; ++k4) {
                        const float4 xv0 = *(const float4*)(xr + k4 * 4);
                        const float4 wv0 = *(const float4*)(wr + k4 * 4);
                        const float4 xv1 = *(const float4*)(xr + 512 + k4 * 4);
                        const float4 wv1 = *(const float4*)(wr + 512 + k4 * 4);
                        a0 = fmaf(xv0.x, wv0.x, a0); a1 = fmaf(xv1.x, wv1.x, a1);
                        a0 = fmaf(xv0.y, wv0.y, a0); a1 = fmaf(xv1.y, wv1.y, a1);
                        a0 = fmaf(xv0.z, wv0.z, a0); a1 = fmaf(xv1.z, wv1.z, a1);
                        a0 = fmaf(xv0.w, wv0.w, a0); a1 = fmaf(xv1.w, wv1.w, a1);
                    }
                    const float tt = ((a0 + a1) + b) * s;
                    dec = (tt >= -0.5f) ? 1.0f : 0.0f;
                } else {
                    dec = (t >= -0.5f) ? 1.0f : 0.0f;
                }
                out[(size_t)m * N_OUT + n] = dec;
            }
        }
    }
}

extern "C" void kernel_launch(void* const* d_in, const int* in_sizes, int n_in,
                              void* d_out, int out_size, void* d_ws, size_t ws_size,
                              hipStream_t stream) {
    const float* x    = (const float*)d_in[0];
    const float* w    = (const float*)d_in[1];
    const float* bias = (const float*)d_in[2];
    const float* sign = (const float*)d_in[3];

    if (n_in >= 4 && in_sizes[0] != M_BATCH * K_IN) {   // defensive no-op
        const float* small[2] = {nullptr, nullptr};
        int nsmall = 0;
        for (int i = 0; i < 4; ++i) {
            if (in_sizes[i] == M_BATCH * K_IN)      x = (const float*)d_in[i];
            else if (in_sizes[i] == N_OUT * K_IN)   w = (const float*)d_in[i];
            else if (nsmall < 2) small[nsmall++] = (const float*)d_in[i];
        }
        if (nsmall == 2) { bias = small[0]; sign = small[1]; }
    }

    float* out = (float*)d_out;
    dim3 grid(N_OUT / BN, M_BATCH / BM);   // (2, 512)
    binlin_mfma<<<grid, 256, 0, stream>>>(x, w, bias, sign, out);
}

// Round 11
// 456.683 us; speedup vs baseline: 1.6794x; 1.6794x over previous
//
#include <hip/hip_runtime.h>

#define M_BATCH 65536
#define K_IN    1024
#define N_OUT   256

#define BM  128
#define BK  64
#define NKT (K_IN / BK)   // 16
#define LDK 72            // 64 + 8 shorts: 16B-aligned rows, low-conflict
#define TAU 0.0625f

typedef __attribute__((ext_vector_type(8))) short short8;   // 8 bf16
typedef __attribute__((ext_vector_type(4))) short short4v;
typedef __attribute__((ext_vector_type(4))) float f32x4;

__device__ inline short f2bf(float f) {          // RNE f32 -> bf16 bits
    unsigned u = __builtin_bit_cast(unsigned, f);
    u += 0x7fff + ((u >> 16) & 1);
    return (short)(u >> 16);
}
__device__ inline float bf2f(short s) {
    unsigned u = ((unsigned)(unsigned short)s) << 16;
    return __builtin_bit_cast(float, u);
}

// Split-bf16 MFMA GEMM, BN = 256 (full N per block -> x streamed once).
// Reg-prefetch pipeline: tile k+1 global loads issued before tile k's MFMA.
// Epilogue: decisions staged as u8 in LDS (overlay), then coalesced float4
// row writes (kills r10's 8.6x write amplification).
// Band cells |t+0.5| < TAU get the C3-exact recompute (r8/r9/r10-verified:
// kc=512 panels, single sequential f32 chain each, cs = p0 + p1).
__global__ __launch_bounds__(512) void binlin_mfma2(const float* __restrict__ x,
                                                    const float* __restrict__ w,
                                                    const float* __restrict__ bias,
                                                    const float* __restrict__ sign,
                                                    float* __restrict__ out) {
    __shared__ __align__(16) unsigned char smem[73728];
    short (*Ah)[LDK] = reinterpret_cast<short(*)[LDK]>(smem);            // 18432B
    short (*Al)[LDK] = reinterpret_cast<short(*)[LDK]>(smem + 18432);    // 18432B
    short (*Bh)[LDK] = reinterpret_cast<short(*)[LDK]>(smem + 36864);    // 36864B

    const int tid  = threadIdx.x;    // 0..511
    const int lane = tid & 63;
    const int wid  = tid >> 6;       // 8 waves: 2 (m) x 4 (n)
    const int wm   = wid >> 2;
    const int wn   = wid & 3;
    const int l15  = lane & 15;
    const int l4   = lane >> 4;
    const int m0   = blockIdx.x * BM;

    const int srow = tid >> 4;        // 0..31 (+q*32)
    const int sk   = (tid & 15) * 4;  // k offset 0..60

    float4 xa[4], wa[8];              // prefetch registers

    f32x4 acc[4][4];
#pragma unroll
    for (int i = 0; i < 4; ++i)
#pragma unroll
        for (int j = 0; j < 4; ++j) acc[i][j] = (f32x4){0.f, 0.f, 0.f, 0.f};

#define LOAD_TILES(KT)                                                          \
    {                                                                           \
        _Pragma("unroll")                                                       \
        for (int q = 0; q < 4; ++q)                                             \
            xa[q] = *(const float4*)(x + (size_t)(m0 + srow + q * 32) * K_IN + (KT) + sk); \
        _Pragma("unroll")                                                       \
        for (int q = 0; q < 8; ++q)                                             \
            wa[q] = *(const float4*)(w + (size_t)(srow + q * 32) * K_IN + (KT) + sk); \
    }

#define STORE_TILES()                                                           \
    {                                                                           \
        _Pragma("unroll")                                                       \
        for (int q = 0; q < 4; ++q) {                                           \
            const int row = srow + q * 32;                                      \
            short4v h, l;                                                       \
            h.x = f2bf(xa[q].x); l.x = f2bf(xa[q].x - bf2f(h.x));               \
            h.y = f2bf(xa[q].y); l.y = f2bf(xa[q].y - bf2f(h.y));               \
            h.z = f2bf(xa[q].z); l.z = f2bf(xa[q].z - bf2f(h.z));               \
            h.w = f2bf(xa[q].w); l.w = f2bf(xa[q].w - bf2f(h.w));               \
            *(short4v*)&Ah[row][sk] = h;                                        \
            *(short4v*)&Al[row][sk] = l;                                        \
        }                                                                       \
        _Pragma("unroll")                                                       \
        for (int q = 0; q < 8; ++q) {                                           \
            const int row = srow + q * 32;                                      \
            short4v h;                                                          \
            h.x = f2bf(wa[q].x); h.y = f2bf(wa[q].y);                           \
            h.z = f2bf(wa[q].z); h.w = f2bf(wa[q].w);                           \
            *(short4v*)&Bh[row][sk] = h;                                        \
        }                                                                       \
    }

    LOAD_TILES(0)
    STORE_TILES()
    __syncthreads();

    for (int kt = 0; kt < NKT; ++kt) {
        if (kt + 1 < NKT) LOAD_TILES((kt + 1) * BK)   // in flight over MFMAs

#pragma unroll
        for (int ks = 0; ks < 2; ++ks) {
            const int ko = ks * 32 + l4 * 8;
            short8 bfr[4], ahi[4], alo[4];
#pragma unroll
            for (int ni = 0; ni < 4; ++ni)
                bfr[ni] = *(const short8*)&Bh[wn * 64 + ni * 16 + l15][ko];
#pragma unroll
            for (int mi = 0; mi < 4; ++mi) {
                ahi[mi] = *(const short8*)&Ah[wm * 64 + mi * 16 + l15][ko];
                alo[mi] = *(const short8*)&Al[wm * 64 + mi * 16 + l15][ko];
            }
#pragma unroll
            for (int mi = 0; mi < 4; ++mi)
#pragma unroll
                for (int ni = 0; ni < 4; ++ni) {
                    acc[mi][ni] = __builtin_amdgcn_mfma_f32_16x16x32_bf16(
                        ahi[mi], bfr[ni], acc[mi][ni], 0, 0, 0);
                    acc[mi][ni] = __builtin_amdgcn_mfma_f32_16x16x32_bf16(
                        alo[mi], bfr[ni], acc[mi][ni], 0, 0, 0);
                }
        }
        __syncthreads();                      // everyone done reading LDS
        if (kt + 1 < NKT) STORE_TILES()       // convert + write next tile
        __syncthreads();
    }

    // ---- epilogue: decide (+ C3-exact band fixup) -> u8 LDS -> coalesced out
    unsigned char* dec = smem;                // overlay, 128*256 = 32KB
#pragma unroll
    for (int ni = 0; ni < 4; ++ni) {
        const int n = wn * 64 + ni * 16 + l15;
        const float b = bias[n];
        const float s = sign[n];
#pragma unroll
        for (int mi = 0; mi < 4; ++mi) {
            const int ml = wm * 64 + mi * 16 + l4 * 4;
#pragma unroll
            for (int j = 0; j < 4; ++j) {
                const float t = (acc[mi][ni][j] + b) * s;
                unsigned char d;
                if (fabsf(t + 0.5f) < TAU) {
                    const float* xr = x + (size_t)(m0 + ml + j) * K_IN;
                    const float* wr = w + (size_t)n * K_IN;
                    float a0 = 0.f, a1 = 0.f;   // two kc=512 panel chains
                    for (int k4 = 0; k4 < 128; ++k4) {
                        const float4 xv0 = *(const float4*)(xr + k4 * 4);
                        const float4 wv0 = *(const float4*)(wr + k4 * 4);
                        const float4 xv1 = *(const float4*)(xr + 512 + k4 * 4);
                        const float4 wv1 = *(const float4*)(wr + 512 + k4 * 4);
                        a0 = fmaf(xv0.x, wv0.x, a0); a1 = fmaf(xv1.x, wv1.x, a1);
                        a0 = fmaf(xv0.y, wv0.y, a0); a1 = fmaf(xv1.y, wv1.y, a1);
                        a0 = fmaf(xv0.z, wv0.z, a0); a1 = fmaf(xv1.z, wv1.z, a1);
                        a0 = fmaf(xv0.w, wv0.w, a0); a1 = fmaf(xv1.w, wv1.w, a1);
                    }
                    const float tt = ((a0 + a1) + b) * s;
                    d = (tt >= -0.5f) ? 1 : 0;
                } else {
                    d = (t >= -0.5f) ? 1 : 0;
                }
                dec[(ml + j) * N_OUT + n] = d;
            }
        }
    }
    __syncthreads();

#pragma unroll
    for (int it = 0; it < 16; ++it) {
        const int f   = it * 512 + tid;   // float4 index in 128x256 tile
        const int row = f >> 6;
        const int c4  = f & 63;
        const uchar4 dv = *(const uchar4*)&dec[row * N_OUT + c4 * 4];
        *(float4*)(out + (size_t)(m0 + row) * N_OUT + c4 * 4) =
            make_float4((float)dv.x, (float)dv.y, (float)dv.z, (float)dv.w);
    }
}

extern "C" void kernel_launch(void* const* d_in, const int* in_sizes, int n_in,
                              void* d_out, int out_size, void* d_ws, size_t ws_size,
                              hipStream_t stream) {
    const float* x    = (const float*)d_in[0];
    const float* w    = (const float*)d_in[1];
    const float* bias = (const float*)d_in[2];
    const float* sign = (const float*)d_in[3];

    if (n_in >= 4 && in_sizes[0] != M_BATCH * K_IN) {   // defensive no-op
        const float* small[2] = {nullptr, nullptr};
        int nsmall = 0;
        for (int i = 0; i < 4; ++i) {
            if (in_sizes[i] == M_BATCH * K_IN)      x = (const float*)d_in[i];
            else if (in_sizes[i] == N_OUT * K_IN)   w = (const float*)d_in[i];
            else if (nsmall < 2) small[nsmall++] = (const float*)d_in[i];
        }
        if (nsmall == 2) { bias = small[0]; sign = small[1]; }
    }

    float* out = (float*)d_out;
    binlin_mfma2<<<M_BATCH / BM, 512, 0, stream>>>(x, w, bias, sign, out);
}